// Round 11
// baseline (10613.889 us; speedup 1.0000x reference)
//
#include <hip/hip_runtime.h>
#include <cstdint>
#include <cstddef>

#define L_SEQ 4096
#define HDIM  1024
#define G3    3072          // 3*HDIM
#define NWG   128           // workgroups per direction (scan)
#define SCAN_THREADS 512    // 8 waves: row = t>>6, 64 k-lanes per row

// ---------------------------------------------------------------------------
// GEMM: GI[s][r] = sum_k X[s][k] * W[r][k] + b[r]   (both operands k-major)
// 128x128 tile, BK=16, 256 threads, 8x8 micro-tile per thread. (unchanged)
// ---------------------------------------------------------------------------
#define BM 128
#define BN 128
#define BK 16
#define LPAD 4

__global__ __launch_bounds__(256) void gi_gemm(
    const float* __restrict__ X,
    const float* __restrict__ Wf, const float* __restrict__ bf,
    const float* __restrict__ Wr, const float* __restrict__ br,
    float* __restrict__ GIf, float* __restrict__ GIr)
{
    const int dir = blockIdx.z;
    const float* W  = dir ? Wr : Wf;
    const float* bi = dir ? br : bf;
    float* GI = dir ? GIr : GIf;

    __shared__ float As[BK][BM + LPAD];
    __shared__ float Bs[BK][BN + LPAD];

    const int t  = threadIdx.x;
    const int s0 = blockIdx.x * BM;
    const int r0 = blockIdx.y * BN;

    const int tr = t >> 4;          // 0..15
    const int tc = t & 15;          // 0..15

    float acc[8][8];
#pragma unroll
    for (int i = 0; i < 8; ++i)
#pragma unroll
        for (int j = 0; j < 8; ++j) acc[i][j] = 0.f;

    const int lrow = t >> 2;        // 0..63
    const int lcol = (t & 3) * 4;   // 0,4,8,12

    for (int k0 = 0; k0 < HDIM; k0 += BK) {
#pragma unroll
        for (int p = 0; p < 2; ++p) {
            const int row = lrow + 64 * p;
            float4 av = *reinterpret_cast<const float4*>(&X[(size_t)(s0 + row) * HDIM + k0 + lcol]);
            float4 bv = *reinterpret_cast<const float4*>(&W[(size_t)(r0 + row) * HDIM + k0 + lcol]);
            As[lcol + 0][row] = av.x; As[lcol + 1][row] = av.y;
            As[lcol + 2][row] = av.z; As[lcol + 3][row] = av.w;
            Bs[lcol + 0][row] = bv.x; Bs[lcol + 1][row] = bv.y;
            Bs[lcol + 2][row] = bv.z; Bs[lcol + 3][row] = bv.w;
        }
        __syncthreads();
#pragma unroll
        for (int kk = 0; kk < BK; ++kk) {
            float4 a0 = *reinterpret_cast<const float4*>(&As[kk][8 * tr]);
            float4 a1 = *reinterpret_cast<const float4*>(&As[kk][8 * tr + 4]);
            float4 b0 = *reinterpret_cast<const float4*>(&Bs[kk][8 * tc]);
            float4 b1 = *reinterpret_cast<const float4*>(&Bs[kk][8 * tc + 4]);
            float a[8] = {a0.x, a0.y, a0.z, a0.w, a1.x, a1.y, a1.z, a1.w};
            float b[8] = {b0.x, b0.y, b0.z, b0.w, b1.x, b1.y, b1.z, b1.w};
#pragma unroll
            for (int i = 0; i < 8; ++i)
#pragma unroll
                for (int j = 0; j < 8; ++j)
                    acc[i][j] = fmaf(a[i], b[j], acc[i][j]);
        }
        __syncthreads();
    }

#pragma unroll
    for (int i = 0; i < 8; ++i) {
        const int row = s0 + 8 * tr + i;
#pragma unroll
        for (int j = 0; j < 8; ++j) acc[i][j] += bi[r0 + 8 * tc + j];
        float4* dst = reinterpret_cast<float4*>(&GI[(size_t)row * G3 + r0 + 8 * tc]);
        dst[0] = make_float4(acc[i][0], acc[i][1], acc[i][2], acc[i][3]);
        dst[1] = make_float4(acc[i][4], acc[i][5], acc[i][6], acc[i][7]);
    }
}

// ---------------------------------------------------------------------------
// Persistent bidirectional GRU scan — R10 structure (8.28 ms measured:
// tagged packets + arrival-driven LDS flag pipeline, no fences/barriers)
// with ONE change: 512 threads/WG so each thread carries only 48 weight
// floats -> genuinely VGPR-resident (R4/R7/R10 all showed VGPR=68..76, i.e.
// the 96/thread layout ALWAYS spilled; the dot re-streamed weights from
// scratch/L2 inside the post-arrival critical path every step).
//
//   * 8 waves/WG. Row r = t>>6 (8 rows/WG), k-lane kp = t&63.
//     Weights wr/wz/wn[16] per thread (k = kp + 64*i), 48 floats.
//   * Poll: thread t polls packets 2t, 2t+1 (16B); stages float2 to h_lds.
//     Wave w stages rows [128w, 128w+128): wflag[par][w] = s+1 when posted.
//   * Arrival-driven dot over 8 chunks of 128 rows; chunk c contributes
//     i = 2c, 2c+1 (6 FMAs). Reduce = 6 shfl levels across the wave.
//   * rdone[par][w] posted after dot reads; stagers gate on rdone (WAR
//     protection for h_lds parity reuse), as proven in R10.
//
// Launch: 256 WGs x 512 thr, 1 WG/CU (proven geometry; R8's 2/CU hung).
// __launch_bounds__(512,1) -> allocator may use up to 256 VGPR/wave: no
// spill. Packet protocol / GI position / out stores identical to R10.
// ---------------------------------------------------------------------------
__global__ __launch_bounds__(SCAN_THREADS, 1) void gru_scan(
    const float* __restrict__ WhhF, const float* __restrict__ WhhR,
    const float* __restrict__ bhhF, const float* __restrict__ bhhR,
    const float* __restrict__ GIf,  const float* __restrict__ GIr,
    float* __restrict__ out,
    unsigned long long* __restrict__ pkF, unsigned long long* __restrict__ pkR)
{
    const int wg  = blockIdx.x;
    const int dir = wg >> 7;            // 0 fwd, 1 rev
    const int wid = wg & (NWG - 1);
    const float* Whh = dir ? WhhR : WhhF;
    const float* bhh = dir ? bhhR : bhhF;
    const float* GI  = dir ? GIr  : GIf;
    unsigned long long* pk = dir ? pkR : pkF;

    const int t  = threadIdx.x;
    const int wv = t >> 6;              // wave id 0..7 (stages chunk wv)
    const int kp = t & 63;              // k-lane within the row's wave
    const int j  = wid * 8 + wv;        // global h index this wave serves

    // weights -> registers (one-time): 16 per gate, k = kp + 64*i
    float wr[16], wz[16], wn[16];
    {
        const float* pr = Whh + (size_t)j * HDIM + kp;
        const float* pz = pr + (size_t)HDIM * HDIM;
        const float* pn = pz + (size_t)HDIM * HDIM;
#pragma unroll
        for (int i = 0; i < 16; ++i) {
            wr[i] = pr[64 * i];
            wz[i] = pz[64 * i];
            wn[i] = pn[64 * i];
        }
    }
#pragma unroll
    for (int i = 0; i < 16; ++i) {
        asm volatile("" : "+v"(wr[i]), "+v"(wz[i]), "+v"(wn[i]));
    }
    const float b_r = bhh[j];
    const float b_z = bhh[HDIM + j];
    const float b_n = bhh[2 * HDIM + j];

    __shared__ float h_lds[2][HDIM];    // double-buffered by step parity
    __shared__ int   wflag[2][8];       // stage flags  [parity][wave-chunk]
    __shared__ int   rdone[2][8];       // consume flags [parity][wave]

    if (t < 16)      wflag[t >> 3][t & 7] = 0;
    else if (t < 32) rdone[(t - 16) >> 3][(t - 16) & 7] = 0;
    __syncthreads();                    // one-time flag init barrier

    // preload GI for step 0 (kp==0 lane of each row-wave)
    float gr = 0.f, gz = 0.f, gn = 0.f;
    if (kp == 0) {
        const float* g = GI + (size_t)(dir ? (L_SEQ - 1) : 0) * G3 + j;
        gr = g[0];
        gz = g[HDIM];
        gn = g[2 * HDIM];
    }

    for (int s = 0; s < L_SEQ; ++s) {
        const int srow = dir ? (L_SEQ - 1 - s) : s;
        const int par  = s & 1;
        const int want = s + 1;         // flag value for this step

        // ---- parity-reuse gate (WAR protection for h_lds[par]) -----------
        if (s >= 2) {
            for (;;) {
                int ok = 1;
#pragma unroll
                for (int w = 0; w < 8; ++w)
                    ok &= (__hip_atomic_load(&rdone[par][w], __ATOMIC_RELAXED,
                                             __HIP_MEMORY_SCOPE_WORKGROUP) >= s - 1);
                if (ok) break;
            }
            __threadfence_block();
        }

        // ---- poll the 2 global packets this thread stages (tag == s) -----
        const unsigned long long* src = pk + (size_t)par * HDIM + 2 * t;
        const unsigned wtag = (unsigned)s;
        unsigned long long p0, p1;
        for (;;) {
            p0 = __hip_atomic_load(src + 0, __ATOMIC_RELAXED, __HIP_MEMORY_SCOPE_AGENT);
            p1 = __hip_atomic_load(src + 1, __ATOMIC_RELAXED, __HIP_MEMORY_SCOPE_AGENT);
            if ((unsigned)(p0 >> 32) == wtag && (unsigned)(p1 >> 32) == wtag)
                break;
        }
        reinterpret_cast<float2*>(h_lds[par])[t] =
            make_float2(__uint_as_float((unsigned)p0), __uint_as_float((unsigned)p1));
        __threadfence_block();          // order h writes before the flag
        if (kp == 0)
            __hip_atomic_store(&wflag[par][wv], want, __ATOMIC_RELAXED, __HIP_MEMORY_SCOPE_WORKGROUP);

        // ---- GI prefetch for step s+1 (R4/R10 position) ------------------
        float gnr = 0.f, gnz = 0.f, gnn = 0.f;
        if (s + 1 < L_SEQ && kp == 0) {
            const int nrow = dir ? (L_SEQ - 2 - s) : (s + 1);
            const float* g = GI + (size_t)nrow * G3 + j;
            gnr = g[0];
            gnz = g[HDIM];
            gnn = g[2 * HDIM];
        }

        // ---- arrival-driven dot: spin per 128-row chunk, then its FMAs ---
        float ar = 0.f, az = 0.f, an = 0.f;
#pragma unroll
        for (int c = 0; c < 8; ++c) {
            for (;;) {
                int f = __hip_atomic_load(&wflag[par][c], __ATOMIC_RELAXED, __HIP_MEMORY_SCOPE_WORKGROUP);
                if (f >= want) break;
            }
            __threadfence_block();
#pragma unroll
            for (int i = 2 * c; i < 2 * c + 2; ++i) {
                const float h = h_lds[par][kp + 64 * i];
                ar = fmaf(wr[i], h, ar);
                az = fmaf(wz[i], h, az);
                an = fmaf(wn[i], h, an);
            }
        }
        const float hold = h_lds[par][j];   // all chunks spun above
        __threadfence_block();              // order h reads before rdone
        if (kp == 0)
            __hip_atomic_store(&rdone[par][wv], want, __ATOMIC_RELAXED, __HIP_MEMORY_SCOPE_WORKGROUP);

        // ---- reduce across the 64 k-lanes of the wave --------------------
#pragma unroll
        for (int off = 32; off > 0; off >>= 1) {
            ar += __shfl_down(ar, off, 64);
            az += __shfl_down(az, off, 64);
            an += __shfl_down(an, off, 64);
        }

        if (kp == 0) {
            const float rr = 1.f / (1.f + __expf(-(gr + ar + b_r)));
            const float zz = 1.f / (1.f + __expf(-(gz + az + b_z)));
            const float xx = gn + rr * (an + b_n);
            const float e  = __expf(-2.f * fabsf(xx));   // overflow-safe tanh
            float th = (1.f - e) / (1.f + e);
            th = copysignf(th, xx);
            const float hn = (1.f - zz) * th + zz * hold;

            // publish FIRST (critical path for every other WG)
            const unsigned long long pkt =
                ((unsigned long long)(unsigned)(s + 1) << 32) | __float_as_uint(hn);
            __hip_atomic_store(pk + (size_t)((s + 1) & 1) * HDIM + j, pkt,
                               __ATOMIC_RELAXED, __HIP_MEMORY_SCOPE_AGENT);

            out[(size_t)srow * (2 * HDIM) + dir * HDIM + j] = hn;
            if (s == L_SEQ - 1) {
                out[(size_t)L_SEQ * 2 * HDIM + dir * HDIM + j] = hn;             // hidden
                out[(size_t)L_SEQ * 2 * HDIM + 2 * HDIM + dir * HDIM + j] = hn;  // projected
            }
        }

        gr = gnr; gz = gnz; gn = gnn;
    }
}

// ---------------------------------------------------------------------------
extern "C" void kernel_launch(void* const* d_in, const int* in_sizes, int n_in,
                              void* d_out, int out_size, void* d_ws, size_t ws_size,
                              hipStream_t stream)
{
    (void)in_sizes; (void)n_in; (void)out_size; (void)ws_size;

    const float* x    = (const float*)d_in[0];
    const float* fWih = (const float*)d_in[1];
    const float* fWhh = (const float*)d_in[2];
    const float* fbih = (const float*)d_in[3];
    const float* fbhh = (const float*)d_in[4];
    const float* rWih = (const float*)d_in[5];
    const float* rWhh = (const float*)d_in[6];
    const float* rbih = (const float*)d_in[7];
    const float* rbhh = (const float*)d_in[8];
    float* out = (float*)d_out;

    // ws layout (bytes):
    //   [0, 16384)      pkF : 2 parities x 1024 x u64
    //   [16384, 32768)  pkR
    //   [32768, ...)    GIf (L*3072 f32), then GIr
    unsigned long long* pkF = (unsigned long long*)d_ws;
    unsigned long long* pkR = pkF + 2 * HDIM;
    float* GIf = (float*)((char*)d_ws + 32768);
    float* GIr = GIf + (size_t)L_SEQ * G3;

    // packets must start as tag=0 value=0.0f (= h_0); ws is poisoned 0xAA
    hipMemsetAsync(d_ws, 0, 32768, stream);

    dim3 gg(L_SEQ / BM, G3 / BN, 2);
    gi_gemm<<<gg, 256, 0, stream>>>(x, fWih, fbih, rWih, rbih, GIf, GIr);

    const float* a0 = fWhh; const float* a1 = rWhh;
    const float* a2 = fbhh; const float* a3 = rbhh;
    const float* a4 = GIf;  const float* a5 = GIr;
    float* a6 = out;
    unsigned long long* a7 = pkF; unsigned long long* a8 = pkR;
    void* args[] = {(void*)&a0, (void*)&a1, (void*)&a2, (void*)&a3,
                    (void*)&a4, (void*)&a5, (void*)&a6, (void*)&a7, (void*)&a8};

    hipError_t err = hipLaunchCooperativeKernel((const void*)gru_scan,
                                                dim3(2 * NWG), dim3(SCAN_THREADS),
                                                args, 0, stream);
    if (err != hipSuccess) {
        // 256 WGs at 1 block/CU on 256 CUs co-reside (proven R4/R6/R7/R10)
        gru_scan<<<dim3(2 * NWG), dim3(SCAN_THREADS), 0, stream>>>(
            fWhh, rWhh, fbhh, rbhh, GIf, GIr, out, pkF, pkR);
    }
}

// Round 12
// 9375.798 us; speedup vs baseline: 1.1321x; 1.1321x over previous
//
#include <hip/hip_runtime.h>
#include <cstdint>
#include <cstddef>

#define L_SEQ 4096
#define HDIM  1024
#define G3    3072          // 3*HDIM
#define NWG   128           // workgroups per direction (scan)
#define SCAN_THREADS 256
// dynamic LDS: weights 3*8*8*32 float4 = 96KB, h double-buffer 8KB
#define DYN_LDS (98304 + 8192)

// ---------------------------------------------------------------------------
// GEMM: GI[s][r] = sum_k X[s][k] * W[r][k] + b[r]   (both operands k-major)
// 128x128 tile, BK=16, 256 threads, 8x8 micro-tile per thread. (unchanged)
// ---------------------------------------------------------------------------
#define BM 128
#define BN 128
#define BK 16
#define LPAD 4

__global__ __launch_bounds__(256) void gi_gemm(
    const float* __restrict__ X,
    const float* __restrict__ Wf, const float* __restrict__ bf,
    const float* __restrict__ Wr, const float* __restrict__ br,
    float* __restrict__ GIf, float* __restrict__ GIr)
{
    const int dir = blockIdx.z;
    const float* W  = dir ? Wr : Wf;
    const float* bi = dir ? br : bf;
    float* GI = dir ? GIr : GIf;

    __shared__ float As[BK][BM + LPAD];
    __shared__ float Bs[BK][BN + LPAD];

    const int t  = threadIdx.x;
    const int s0 = blockIdx.x * BM;
    const int r0 = blockIdx.y * BN;

    const int tr = t >> 4;          // 0..15
    const int tc = t & 15;          // 0..15

    float acc[8][8];
#pragma unroll
    for (int i = 0; i < 8; ++i)
#pragma unroll
        for (int j = 0; j < 8; ++j) acc[i][j] = 0.f;

    const int lrow = t >> 2;        // 0..63
    const int lcol = (t & 3) * 4;   // 0,4,8,12

    for (int k0 = 0; k0 < HDIM; k0 += BK) {
#pragma unroll
        for (int p = 0; p < 2; ++p) {
            const int row = lrow + 64 * p;
            float4 av = *reinterpret_cast<const float4*>(&X[(size_t)(s0 + row) * HDIM + k0 + lcol]);
            float4 bv = *reinterpret_cast<const float4*>(&W[(size_t)(r0 + row) * HDIM + k0 + lcol]);
            As[lcol + 0][row] = av.x; As[lcol + 1][row] = av.y;
            As[lcol + 2][row] = av.z; As[lcol + 3][row] = av.w;
            Bs[lcol + 0][row] = bv.x; Bs[lcol + 1][row] = bv.y;
            Bs[lcol + 2][row] = bv.z; Bs[lcol + 3][row] = bv.w;
        }
        __syncthreads();
#pragma unroll
        for (int kk = 0; kk < BK; ++kk) {
            float4 a0 = *reinterpret_cast<const float4*>(&As[kk][8 * tr]);
            float4 a1 = *reinterpret_cast<const float4*>(&As[kk][8 * tr + 4]);
            float4 b0 = *reinterpret_cast<const float4*>(&Bs[kk][8 * tc]);
            float4 b1 = *reinterpret_cast<const float4*>(&Bs[kk][8 * tc + 4]);
            float a[8] = {a0.x, a0.y, a0.z, a0.w, a1.x, a1.y, a1.z, a1.w};
            float b[8] = {b0.x, b0.y, b0.z, b0.w, b1.x, b1.y, b1.z, b1.w};
#pragma unroll
            for (int i = 0; i < 8; ++i)
#pragma unroll
                for (int j = 0; j < 8; ++j)
                    acc[i][j] = fmaf(a[i], b[j], acc[i][j]);
        }
        __syncthreads();
    }

#pragma unroll
    for (int i = 0; i < 8; ++i) {
        const int row = s0 + 8 * tr + i;
#pragma unroll
        for (int j = 0; j < 8; ++j) acc[i][j] += bi[r0 + 8 * tc + j];
        float4* dst = reinterpret_cast<float4*>(&GI[(size_t)row * G3 + r0 + 8 * tc]);
        dst[0] = make_float4(acc[i][0], acc[i][1], acc[i][2], acc[i][3]);
        dst[1] = make_float4(acc[i][4], acc[i][5], acc[i][6], acc[i][7]);
    }
}

// ---------------------------------------------------------------------------
// Persistent bidirectional GRU scan — R10 structure EXACTLY (8.28 ms:
// tagged packets + arrival-driven LDS flag pipeline, 256 WGs x 256 thr,
// 1 WG/CU) with ONE change:
//
//   WEIGHTS IN DYNAMIC LDS (96 KB fp32). R6/R10/R11 proved the allocator
//   NEVER keeps the weight array in VGPRs (68/132/48 regs; R11 even spilled
//   loop state per step, WRITE +124 MB). Every step the dot re-streamed
//   ~96 scratch/L2 loads per thread inside the post-arrival critical path.
//   LDS residency is deterministic: dot = 24 ds_read_b128 (weights, packed
//   float4 per gate x k-quad) + 8 ds_read_b128 (h, half-wave broadcast)
//   + 96 FMAs ~= 200ns, conflict-free.
//
//   k mapping: k = 4*kp + 128*i4 + c (kp=t&31, i4=0..7, c=0..3 within the
//   float4). wl4[g][i4][r][kp]; each thread writes then reads ONLY its own
//   entries (no barrier needed). h read as float4 at index kp+32*i4.
//   Chunk c of the arrival pipeline (h rows [256c,256c+256)) = i4 {2c,2c+1}.
//
// Dynamic LDS 104 KB via hipFuncSetAttribute (m201's 8-phase GEMM proves
// >64KB/WG works in plain HIP on gfx950). Geometry stays 1 WG/CU.
// Packet protocol / GI position / flags / reduce: identical to R10.
// ---------------------------------------------------------------------------
__global__ __launch_bounds__(SCAN_THREADS, 1) void gru_scan(
    const float* __restrict__ WhhF, const float* __restrict__ WhhR,
    const float* __restrict__ bhhF, const float* __restrict__ bhhR,
    const float* __restrict__ GIf,  const float* __restrict__ GIr,
    float* __restrict__ out,
    unsigned long long* __restrict__ pkF, unsigned long long* __restrict__ pkR)
{
    extern __shared__ float smem[];
    float4* wl4  = reinterpret_cast<float4*>(smem);   // [3][8][8][32] float4
    float*  hbuf = smem + 24576;                      // [2][1024] floats

    const int wg  = blockIdx.x;
    const int dir = wg >> 7;            // 0 fwd, 1 rev
    const int wid = wg & (NWG - 1);
    const float* Whh = dir ? WhhR : WhhF;
    const float* bhh = dir ? bhhR : bhhF;
    const float* GI  = dir ? GIr  : GIf;
    unsigned long long* pk = dir ? pkR : pkF;

    const int t     = threadIdx.x;
    const int wv    = t >> 6;           // wave id 0..3 (stages chunk wv)
    const int r_idx = t >> 5;           // 0..7 (row within WG)
    const int kp    = t & 31;           // 0..31 (k-lane within row group)
    const int j     = wid * 8 + r_idx;  // global h index this group serves

    // ---- weights -> LDS, packed float4 (one-time, coalesced) -------------
#pragma unroll
    for (int g = 0; g < 3; ++g)
#pragma unroll
        for (int i4 = 0; i4 < 8; ++i4) {
            const float* gsrc = Whh + (size_t)(g * HDIM + j) * HDIM + 128 * i4 + 4 * kp;
            wl4[((g * 8 + i4) * 8 + r_idx) * 32 + kp] = *reinterpret_cast<const float4*>(gsrc);
        }

    const float b_r = bhh[j];
    const float b_z = bhh[HDIM + j];
    const float b_n = bhh[2 * HDIM + j];

    __shared__ int wflag[2][4];         // stage flags  [parity][wave-chunk]
    __shared__ int rdone[2][4];         // consume flags [parity][wave]
    if (t < 8)       wflag[t >> 2][t & 3] = 0;
    else if (t < 16) rdone[(t - 8) >> 2][(t - 8) & 3] = 0;
    __syncthreads();                    // one-time init barrier

    // preload GI for step 0
    float gr = 0.f, gz = 0.f, gn = 0.f;
    if (kp == 0) {
        const float* g = GI + (size_t)(dir ? (L_SEQ - 1) : 0) * G3 + j;
        gr = g[0];
        gz = g[HDIM];
        gn = g[2 * HDIM];
    }

    for (int s = 0; s < L_SEQ; ++s) {
        const int srow = dir ? (L_SEQ - 1 - s) : s;
        const int par  = s & 1;
        const int want = s + 1;         // flag value for this step

        // ---- parity-reuse gate (WAR protection for hbuf[par]) ------------
        if (s >= 2) {
            for (;;) {
                int d0 = __hip_atomic_load(&rdone[par][0], __ATOMIC_RELAXED, __HIP_MEMORY_SCOPE_WORKGROUP);
                int d1 = __hip_atomic_load(&rdone[par][1], __ATOMIC_RELAXED, __HIP_MEMORY_SCOPE_WORKGROUP);
                int d2 = __hip_atomic_load(&rdone[par][2], __ATOMIC_RELAXED, __HIP_MEMORY_SCOPE_WORKGROUP);
                int d3 = __hip_atomic_load(&rdone[par][3], __ATOMIC_RELAXED, __HIP_MEMORY_SCOPE_WORKGROUP);
                if (d0 >= s - 1 && d1 >= s - 1 && d2 >= s - 1 && d3 >= s - 1) break;
            }
            __threadfence_block();
        }

        // ---- poll the 4 global packets this thread stages (tag == s) -----
        const unsigned long long* src = pk + (size_t)par * HDIM + 4 * t;
        const unsigned wtag = (unsigned)s;
        unsigned long long p0, p1, p2, p3;
        for (;;) {
            p0 = __hip_atomic_load(src + 0, __ATOMIC_RELAXED, __HIP_MEMORY_SCOPE_AGENT);
            p1 = __hip_atomic_load(src + 1, __ATOMIC_RELAXED, __HIP_MEMORY_SCOPE_AGENT);
            p2 = __hip_atomic_load(src + 2, __ATOMIC_RELAXED, __HIP_MEMORY_SCOPE_AGENT);
            p3 = __hip_atomic_load(src + 3, __ATOMIC_RELAXED, __HIP_MEMORY_SCOPE_AGENT);
            if ((unsigned)(p0 >> 32) == wtag && (unsigned)(p1 >> 32) == wtag &&
                (unsigned)(p2 >> 32) == wtag && (unsigned)(p3 >> 32) == wtag)
                break;
        }
        reinterpret_cast<float4*>(hbuf + (size_t)par * HDIM)[t] =
            make_float4(__uint_as_float((unsigned)p0), __uint_as_float((unsigned)p1),
                        __uint_as_float((unsigned)p2), __uint_as_float((unsigned)p3));
        __threadfence_block();          // order h writes before the flag
        if ((t & 63) == 0)
            __hip_atomic_store(&wflag[par][wv], want, __ATOMIC_RELAXED, __HIP_MEMORY_SCOPE_WORKGROUP);

        // ---- GI prefetch for step s+1 (R4/R10 position) ------------------
        float gnr = 0.f, gnz = 0.f, gnn = 0.f;
        if (s + 1 < L_SEQ && kp == 0) {
            const int nrow = dir ? (L_SEQ - 2 - s) : (s + 1);
            const float* g = GI + (size_t)nrow * G3 + j;
            gnr = g[0];
            gnz = g[HDIM];
            gnn = g[2 * HDIM];
        }

        // ---- arrival-driven dot from LDS (b128 weights + b128 h) ---------
        const float4* h4 = reinterpret_cast<const float4*>(hbuf + (size_t)par * HDIM);
        float ar = 0.f, az = 0.f, an = 0.f;
#pragma unroll
        for (int c = 0; c < 4; ++c) {
            for (;;) {
                int f = __hip_atomic_load(&wflag[par][c], __ATOMIC_RELAXED, __HIP_MEMORY_SCOPE_WORKGROUP);
                if (f >= want) break;
            }
            __threadfence_block();
#pragma unroll
            for (int i4 = 2 * c; i4 < 2 * c + 2; ++i4) {
                const float4 hv = h4[kp + 32 * i4];
                const float4 w0 = wl4[((0 * 8 + i4) * 8 + r_idx) * 32 + kp];
                const float4 w1 = wl4[((1 * 8 + i4) * 8 + r_idx) * 32 + kp];
                const float4 w2 = wl4[((2 * 8 + i4) * 8 + r_idx) * 32 + kp];
                ar = fmaf(w0.x, hv.x, fmaf(w0.y, hv.y, fmaf(w0.z, hv.z, fmaf(w0.w, hv.w, ar))));
                az = fmaf(w1.x, hv.x, fmaf(w1.y, hv.y, fmaf(w1.z, hv.z, fmaf(w1.w, hv.w, az))));
                an = fmaf(w2.x, hv.x, fmaf(w2.y, hv.y, fmaf(w2.z, hv.z, fmaf(w2.w, hv.w, an))));
            }
        }
        const float hold = hbuf[(size_t)par * HDIM + j];   // all chunks arrived
        __threadfence_block();              // order h reads before rdone
        if ((t & 63) == 0)
            __hip_atomic_store(&rdone[par][wv], want, __ATOMIC_RELAXED, __HIP_MEMORY_SCOPE_WORKGROUP);

        // ---- reduce across the 32 k-lanes --------------------------------
#pragma unroll
        for (int off = 16; off > 0; off >>= 1) {
            ar += __shfl_down(ar, off, 32);
            az += __shfl_down(az, off, 32);
            an += __shfl_down(an, off, 32);
        }

        if (kp == 0) {
            const float rr = 1.f / (1.f + __expf(-(gr + ar + b_r)));
            const float zz = 1.f / (1.f + __expf(-(gz + az + b_z)));
            const float xx = gn + rr * (an + b_n);
            const float e  = __expf(-2.f * fabsf(xx));   // overflow-safe tanh
            float th = (1.f - e) / (1.f + e);
            th = copysignf(th, xx);
            const float hn = (1.f - zz) * th + zz * hold;

            // publish FIRST (critical path for every other WG)
            const unsigned long long pkt =
                ((unsigned long long)(unsigned)(s + 1) << 32) | __float_as_uint(hn);
            __hip_atomic_store(pk + (size_t)((s + 1) & 1) * HDIM + j, pkt,
                               __ATOMIC_RELAXED, __HIP_MEMORY_SCOPE_AGENT);

            out[(size_t)srow * (2 * HDIM) + dir * HDIM + j] = hn;
            if (s == L_SEQ - 1) {
                out[(size_t)L_SEQ * 2 * HDIM + dir * HDIM + j] = hn;             // hidden
                out[(size_t)L_SEQ * 2 * HDIM + 2 * HDIM + dir * HDIM + j] = hn;  // projected
            }
        }

        gr = gnr; gz = gnz; gn = gnn;
    }
}

// ---------------------------------------------------------------------------
extern "C" void kernel_launch(void* const* d_in, const int* in_sizes, int n_in,
                              void* d_out, int out_size, void* d_ws, size_t ws_size,
                              hipStream_t stream)
{
    (void)in_sizes; (void)n_in; (void)out_size; (void)ws_size;

    const float* x    = (const float*)d_in[0];
    const float* fWih = (const float*)d_in[1];
    const float* fWhh = (const float*)d_in[2];
    const float* fbih = (const float*)d_in[3];
    const float* fbhh = (const float*)d_in[4];
    const float* rWih = (const float*)d_in[5];
    const float* rWhh = (const float*)d_in[6];
    const float* rbih = (const float*)d_in[7];
    const float* rbhh = (const float*)d_in[8];
    float* out = (float*)d_out;

    // ws layout (bytes):
    //   [0, 16384)      pkF : 2 parities x 1024 x u64
    //   [16384, 32768)  pkR
    //   [32768, ...)    GIf (L*3072 f32), then GIr
    unsigned long long* pkF = (unsigned long long*)d_ws;
    unsigned long long* pkR = pkF + 2 * HDIM;
    float* GIf = (float*)((char*)d_ws + 32768);
    float* GIr = GIf + (size_t)L_SEQ * G3;

    // packets must start as tag=0 value=0.0f (= h_0); ws is poisoned 0xAA
    hipMemsetAsync(d_ws, 0, 32768, stream);

    dim3 gg(L_SEQ / BM, G3 / BN, 2);
    gi_gemm<<<gg, 256, 0, stream>>>(x, fWih, fbih, rWih, rbih, GIf, GIr);

    // allow 104 KB dynamic LDS (gfx950 supports up to 160 KB/WG; host-side
    // attribute call, idempotent, no stream op -> graph-capture safe)
    hipFuncSetAttribute(reinterpret_cast<const void*>(gru_scan),
                        hipFuncAttributeMaxDynamicSharedMemorySize, DYN_LDS);

    const float* a0 = fWhh; const float* a1 = rWhh;
    const float* a2 = fbhh; const float* a3 = rbhh;
    const float* a4 = GIf;  const float* a5 = GIr;
    float* a6 = out;
    unsigned long long* a7 = pkF; unsigned long long* a8 = pkR;
    void* args[] = {(void*)&a0, (void*)&a1, (void*)&a2, (void*)&a3,
                    (void*)&a4, (void*)&a5, (void*)&a6, (void*)&a7, (void*)&a8};

    hipError_t err = hipLaunchCooperativeKernel((const void*)gru_scan,
                                                dim3(2 * NWG), dim3(SCAN_THREADS),
                                                args, DYN_LDS, stream);
    if (err != hipSuccess) {
        // 256 WGs at 1 block/CU on 256 CUs co-reside (proven R4/R6/R7/R10)
        gru_scan<<<dim3(2 * NWG), dim3(SCAN_THREADS), DYN_LDS, stream>>>(
            fWhh, rWhh, fbhh, rbhh, GIf, GIr, out, pkF, pkR);
    }
}